// Round 1
// baseline (211.352 us; speedup 1.0000x reference)
//
#include <hip/hip_runtime.h>
#include <hip/hip_bf16.h>
#include <math.h>

#define BATCH_N 8192
#define K_DIM   2048
#define CLS     1000

typedef __attribute__((ext_vector_type(8))) short short8;
typedef __attribute__((ext_vector_type(8))) unsigned short ushort8;
typedef __attribute__((ext_vector_type(4))) float floatx4;

constexpr int BM = 128, BN = 128, BK = 64;
constexpr int LDP = BK + 8;   // +8 bf16 = +16B pad: breaks 128B row stride, 2-way max conflict (free)
constexpr int NKT = K_DIM / BK; // 32

static __device__ __forceinline__ ushort f2bf(float f) {
    union { float f; unsigned u; } v; v.f = f;
    unsigned u = v.u;
    return (ushort)((u + 0x7FFFu + ((u >> 16) & 1u)) >> 16); // RNE
}

// out[m,n] = softplus(X[m,:] . W[n,:] + bias[n]) + 1
__global__ __launch_bounds__(256, 2)
void gemm_alpha(const float* __restrict__ Xa, const float* __restrict__ Xb,
                const float* __restrict__ Wa, const float* __restrict__ Wb,
                const float* __restrict__ ba, const float* __restrict__ bb,
                float* __restrict__ outa, float* __restrict__ outb)
{
    const float* X   = blockIdx.z ? Xb : Xa;
    const float* W   = blockIdx.z ? Wb : Wa;
    const float* bias= blockIdx.z ? bb : ba;
    float* out       = blockIdx.z ? outb : outa;

    __shared__ ushort As[BM][LDP];
    __shared__ ushort Bs[BN][LDP];

    const int tid  = threadIdx.x;
    const int brow = blockIdx.y * BM;
    const int bcol = blockIdx.x * BN;

    float4 ra[4][2], rb[4][2];

    auto load_tile = [&](int kt) {
        const int kbase = kt * BK;
#pragma unroll
        for (int i = 0; i < 4; ++i) {
            int idx = tid + i * 256;       // 0..1023 over [128 rows][8 chunks-of-8]
            int row = idx >> 3;
            int c8  = (idx & 7) << 3;
            const float* pA = X + (size_t)(brow + row) * K_DIM + kbase + c8;
            ra[i][0] = *(const float4*)pA;
            ra[i][1] = *(const float4*)(pA + 4);
            int wrow = bcol + row; if (wrow >= CLS) wrow = CLS - 1; // clamp pad rows
            const float* pB = W + (size_t)wrow * K_DIM + kbase + c8;
            rb[i][0] = *(const float4*)pB;
            rb[i][1] = *(const float4*)(pB + 4);
        }
    };

    auto store_tile = [&]() {
#pragma unroll
        for (int i = 0; i < 4; ++i) {
            int idx = tid + i * 256;
            int row = idx >> 3;
            int c8  = (idx & 7) << 3;
            ushort8 ta, tb;
#pragma unroll
            for (int j = 0; j < 4; ++j) {
                ta[j]     = f2bf(((const float*)&ra[i][0])[j]);
                ta[j + 4] = f2bf(((const float*)&ra[i][1])[j]);
                tb[j]     = f2bf(((const float*)&rb[i][0])[j]);
                tb[j + 4] = f2bf(((const float*)&rb[i][1])[j]);
            }
            *(ushort8*)&As[row][c8] = ta;
            *(ushort8*)&Bs[row][c8] = tb;
        }
    };

    const int lane = tid & 63;
    const int wid  = tid >> 6;
    const int wr = wid >> 1, wc = wid & 1;     // 2x2 waves, 64x64 each
    const int row0 = wr * 64, col0 = wc * 64;
    const int fr = lane & 15;                  // row (A) / col (B,C)
    const int fg = lane >> 4;                  // k-group; C rows fg*4+j

    floatx4 acc[4][4];
#pragma unroll
    for (int m = 0; m < 4; ++m)
#pragma unroll
        for (int n = 0; n < 4; ++n)
            acc[m][n] = (floatx4){0.f, 0.f, 0.f, 0.f};

    load_tile(0);
    for (int kt = 0; kt < NKT; ++kt) {
        if (kt) __syncthreads();          // prev compute done before overwrite
        store_tile();
        __syncthreads();
        if (kt + 1 < NKT) load_tile(kt + 1);   // global latency hides under MFMA
#pragma unroll
        for (int kk = 0; kk < 2; ++kk) {
            short8 af[4], bf8[4];
#pragma unroll
            for (int m = 0; m < 4; ++m)
                af[m] = *(const short8*)&As[row0 + m * 16 + fr][kk * 32 + fg * 8];
#pragma unroll
            for (int n = 0; n < 4; ++n)
                bf8[n] = *(const short8*)&Bs[col0 + n * 16 + fr][kk * 32 + fg * 8];
#pragma unroll
            for (int m = 0; m < 4; ++m)
#pragma unroll
                for (int n = 0; n < 4; ++n)
                    acc[m][n] = __builtin_amdgcn_mfma_f32_16x16x32_bf16(
                        af[m], bf8[n], acc[m][n], 0, 0, 0);
        }
    }

    // epilogue: alpha = softplus(z) + 1, predicated on col < 1000
#pragma unroll
    for (int n = 0; n < 4; ++n) {
        int col = bcol + col0 + n * 16 + fr;
        if (col >= CLS) continue;
        float bv = bias[col];
#pragma unroll
        for (int m = 0; m < 4; ++m) {
#pragma unroll
            for (int j = 0; j < 4; ++j) {
                int row = brow + row0 + m * 16 + fg * 4 + j;
                float z = acc[m][n][j] + bv;
                float s = fmaxf(z, 0.f) + log1pf(expf(-fabsf(z)));
                out[(size_t)row * CLS + col] = s + 1.f;
            }
        }
    }
}

// one block per batch row: Dempster-Shafer combination of two Dirichlet alphas
__global__ __launch_bounds__(256)
void ds_combine(const float* __restrict__ AX, const float* __restrict__ AY,
                float* __restrict__ out)
{
    const int row = blockIdx.x;
    const int t = threadIdx.x;
    const float* ax = AX + (size_t)row * CLS;
    const float* ay = AY + (size_t)row * CLS;

    float4 vx = make_float4(0.f, 0.f, 0.f, 0.f);
    float4 vy = make_float4(0.f, 0.f, 0.f, 0.f);
    const bool act = t < (CLS / 4);   // 250 threads x float4 = 1000
    if (act) {
        vx = *(const float4*)(ax + t * 4);
        vy = *(const float4*)(ay + t * 4);
    }
    float sx = 0.f, sy = 0.f, sp = 0.f;
    if (act) {
        const float* px = (const float*)&vx;
        const float* py = (const float*)&vy;
#pragma unroll
        for (int j = 0; j < 4; ++j) {
            sx += px[j]; sy += py[j];
            sp += (px[j] - 1.f) * (py[j] - 1.f);
        }
    }
#pragma unroll
    for (int off = 32; off > 0; off >>= 1) {
        sx += __shfl_down(sx, off);
        sy += __shfl_down(sy, off);
        sp += __shfl_down(sp, off);
    }
    __shared__ float red[3][4];
    const int lane = t & 63, w = t >> 6;
    if (lane == 0) { red[0][w] = sx; red[1][w] = sy; red[2][w] = sp; }
    __syncthreads();
    const float S1 = red[0][0] + red[0][1] + red[0][2] + red[0][3];
    const float S2 = red[1][0] + red[1][1] + red[1][2] + red[1][3];
    const float P  = red[2][0] + red[2][1] + red[2][2] + red[2][3];

    const float i1 = 1.f / S1, i2 = 1.f / S2;
    const float u1 = (float)CLS * i1, u2 = (float)CLS * i2;
    const float sb1 = (S1 - (float)CLS) * i1;
    const float sb2 = (S2 - (float)CLS) * i2;
    const float conf = sb1 * sb2 - P * i1 * i2;      // bb_sum - bb_diag
    const float denom = 1.f - conf;
    const float idenom = 1.f / denom;
    const float Sa = (float)CLS * denom / (u1 * u2);

    if (act) {
        float4 vo;
        const float* px = (const float*)&vx;
        const float* py = (const float*)&vy;
        float* po = (float*)&vo;
#pragma unroll
        for (int j = 0; j < 4; ++j) {
            float b1 = (px[j] - 1.f) * i1;
            float b2 = (py[j] - 1.f) * i2;
            float ba = (b1 * b2 + b1 * u2 + b2 * u1) * idenom;
            po[j] = ba * Sa + 1.f;
        }
        *(float4*)(out + (size_t)row * CLS + t * 4) = vo;
    }
}

extern "C" void kernel_launch(void* const* d_in, const int* in_sizes, int n_in,
                              void* d_out, int out_size, void* d_ws, size_t ws_size,
                              hipStream_t stream) {
    const float* x  = (const float*)d_in[0];
    const float* y  = (const float*)d_in[1];
    const float* Wx = (const float*)d_in[2];
    const float* bx = (const float*)d_in[3];
    const float* Wy = (const float*)d_in[4];
    const float* by = (const float*)d_in[5];
    float* out = (float*)d_out;
    float* ax = out + (size_t)BATCH_N * CLS;  // output 1: alpha_x
    float* ay = ax  + (size_t)BATCH_N * CLS;  // output 2: alpha_y

    dim3 grid((CLS + BN - 1) / BN, BATCH_N / BM, 2);   // 8 x 64 x 2
    gemm_alpha<<<grid, 256, 0, stream>>>(x, y, Wx, Wy, bx, by, ax, ay);
    ds_combine<<<BATCH_N, 256, 0, stream>>>(ax, ay, out);
}

// Round 2
// 196.645 us; speedup vs baseline: 1.0748x; 1.0748x over previous
//
#include <hip/hip_runtime.h>
#include <hip/hip_bf16.h>
#include <math.h>

#define BATCH_N 8192
#define K_DIM   2048
#define CLS     1000
#define NPAD    1024

typedef __attribute__((ext_vector_type(8))) short short8;
typedef __attribute__((ext_vector_type(8))) unsigned short ushort8;
typedef __attribute__((ext_vector_type(4))) float floatx4;

static __device__ __forceinline__ ushort f2bf(float f) {
    union { float f; unsigned u; } v; v.f = f;
    unsigned u = v.u;
    return (ushort)((u + 0x7FFFu + ((u >> 16) & 1u)) >> 16); // RNE
}

static __device__ __forceinline__ void gld_lds16(const void* g, void* l) {
    __builtin_amdgcn_global_load_lds(
        (const __attribute__((address_space(1))) void*)g,
        (__attribute__((address_space(3))) void*)l, 16, 0, 0);
}

// ---------------- fast path: pre-convert to bf16 in workspace ----------------

// x/y: [8192][2048] f32 -> bf16, 8 elems/thread
__global__ __launch_bounds__(256)
void convert_xy(const float* __restrict__ x, const float* __restrict__ y,
                ushort* __restrict__ ox, ushort* __restrict__ oy)
{
    const float* src = blockIdx.z ? y : x;
    ushort* dst      = blockIdx.z ? oy : ox;
    size_t e = ((size_t)blockIdx.x * 256 + threadIdx.x) * 8;
    float4 a = *(const float4*)(src + e);
    float4 b = *(const float4*)(src + e + 4);
    ushort8 t;
#pragma unroll
    for (int j = 0; j < 4; ++j) {
        t[j]     = f2bf(((const float*)&a)[j]);
        t[j + 4] = f2bf(((const float*)&b)[j]);
    }
    *(ushort8*)(dst + e) = t;
}

// W: [1000][2048] f32 -> [1024][2048] bf16, zero-padded rows
__global__ __launch_bounds__(256)
void convert_w(const float* __restrict__ wx, const float* __restrict__ wy,
               ushort* __restrict__ owx, ushort* __restrict__ owy)
{
    const float* src = blockIdx.z ? wy : wx;
    ushort* dst      = blockIdx.z ? owy : owx;
    size_t e = ((size_t)blockIdx.x * 256 + threadIdx.x) * 8;
    int row = (int)(e >> 11);
    ushort8 t = (ushort8)0;
    if (row < CLS) {
        float4 a = *(const float4*)(src + e);
        float4 b = *(const float4*)(src + e + 4);
#pragma unroll
        for (int j = 0; j < 4; ++j) {
            t[j]     = f2bf(((const float*)&a)[j]);
            t[j + 4] = f2bf(((const float*)&b)[j]);
        }
    }
    *(ushort8*)(dst + e) = t;
}

// bf16 GEMM, m97 structure: 128x128 tile, BK=64, global_load_lds staging.
// out[m,n] = softplus(A[m,:] . B[n,:] + bias[n]) + 1   (B pre-padded to 1024 rows)
constexpr int BM = 128, BN = 128, BK = 64;
constexpr int NKT = K_DIM / BK; // 32

__global__ __launch_bounds__(256)
void gemm_bf16(const ushort* __restrict__ Aa, const ushort* __restrict__ Ab,
               const ushort* __restrict__ Ba, const ushort* __restrict__ Bb,
               const float* __restrict__ biasa, const float* __restrict__ biasb,
               float* __restrict__ outa, float* __restrict__ outb)
{
    const ushort* A   = blockIdx.z ? Ab : Aa;
    const ushort* B   = blockIdx.z ? Bb : Ba;
    const float* bias = blockIdx.z ? biasb : biasa;
    float* out        = blockIdx.z ? outb : outa;

    __shared__ ushort As[BM * BK];   // [128][64] row-major, linear (gld_lds dest)
    __shared__ ushort Bs[BN * BK];

    const int tid  = threadIdx.x;
    const int lane = tid & 63;
    const int wid  = tid >> 6;
    const int brow = blockIdx.y * BM;
    const int bcol = blockIdx.x * BN;

    // per-(instr,wave) linear LDS chunk: 1024B each; global source matches
    const int lelem0 = wid * 512 + lane * 8;    // element offset within instr-chunk group

    const int wr = wid >> 1, wc = wid & 1;      // 2x2 waves, 64x64 each
    const int row0 = wr * 64, col0 = wc * 64;
    const int fr = lane & 15;
    const int fg = lane >> 4;

    floatx4 acc[4][4];
#pragma unroll
    for (int m = 0; m < 4; ++m)
#pragma unroll
        for (int n = 0; n < 4; ++n)
            acc[m][n] = (floatx4){0.f, 0.f, 0.f, 0.f};

    for (int kt = 0; kt < NKT; ++kt) {
        const int kbase = kt * BK;
#pragma unroll
        for (int i = 0; i < 4; ++i) {
            int elem = i * 2048 + lelem0;       // 0..8191 over [128 rows][64 cols]
            int row = elem >> 6, col = elem & 63;
            gld_lds16(A + (size_t)(brow + row) * K_DIM + kbase + col,
                      As + i * 2048 + wid * 512);
            gld_lds16(B + (size_t)(bcol + row) * K_DIM + kbase + col,
                      Bs + i * 2048 + wid * 512);
        }
        __syncthreads();   // drains vmcnt -> tiles resident
#pragma unroll
        for (int kk = 0; kk < 2; ++kk) {
            short8 af[4], bf8[4];
#pragma unroll
            for (int m = 0; m < 4; ++m)
                af[m] = *(const short8*)&As[(row0 + m * 16 + fr) * BK + kk * 32 + fg * 8];
#pragma unroll
            for (int n = 0; n < 4; ++n)
                bf8[n] = *(const short8*)&Bs[(col0 + n * 16 + fr) * BK + kk * 32 + fg * 8];
#pragma unroll
            for (int m = 0; m < 4; ++m)
#pragma unroll
                for (int n = 0; n < 4; ++n)
                    acc[m][n] = __builtin_amdgcn_mfma_f32_16x16x32_bf16(
                        af[m], bf8[n], acc[m][n], 0, 0, 0);
        }
        __syncthreads();   // compute done before next stage overwrites
    }

#pragma unroll
    for (int n = 0; n < 4; ++n) {
        int col = bcol + col0 + n * 16 + fr;
        if (col >= CLS) continue;
        float bv = bias[col];
#pragma unroll
        for (int m = 0; m < 4; ++m) {
#pragma unroll
            for (int j = 0; j < 4; ++j) {
                int row = brow + row0 + m * 16 + fg * 4 + j;
                float z = acc[m][n][j] + bv;
                float s = fmaxf(z, 0.f) + log1pf(expf(-fabsf(z)));
                out[(size_t)row * CLS + col] = s + 1.f;
            }
        }
    }
}

// ---------------- fallback path (round-1): fused fp32->bf16 in-kernel --------

constexpr int LDP = BK + 8;

__global__ __launch_bounds__(256, 2)
void gemm_alpha(const float* __restrict__ Xa, const float* __restrict__ Xb,
                const float* __restrict__ Wa, const float* __restrict__ Wb,
                const float* __restrict__ ba, const float* __restrict__ bb,
                float* __restrict__ outa, float* __restrict__ outb)
{
    const float* X   = blockIdx.z ? Xb : Xa;
    const float* W   = blockIdx.z ? Wb : Wa;
    const float* bias= blockIdx.z ? bb : ba;
    float* out       = blockIdx.z ? outb : outa;

    __shared__ ushort As[BM][LDP];
    __shared__ ushort Bs[BN][LDP];

    const int tid  = threadIdx.x;
    const int brow = blockIdx.y * BM;
    const int bcol = blockIdx.x * BN;

    float4 ra[4][2], rb[4][2];

    auto load_tile = [&](int kt) {
        const int kbase = kt * BK;
#pragma unroll
        for (int i = 0; i < 4; ++i) {
            int idx = tid + i * 256;
            int row = idx >> 3;
            int c8  = (idx & 7) << 3;
            const float* pA = X + (size_t)(brow + row) * K_DIM + kbase + c8;
            ra[i][0] = *(const float4*)pA;
            ra[i][1] = *(const float4*)(pA + 4);
            int wrow = bcol + row; if (wrow >= CLS) wrow = CLS - 1;
            const float* pB = W + (size_t)wrow * K_DIM + kbase + c8;
            rb[i][0] = *(const float4*)pB;
            rb[i][1] = *(const float4*)(pB + 4);
        }
    };

    auto store_tile = [&]() {
#pragma unroll
        for (int i = 0; i < 4; ++i) {
            int idx = tid + i * 256;
            int row = idx >> 3;
            int c8  = (idx & 7) << 3;
            ushort8 ta, tb;
#pragma unroll
            for (int j = 0; j < 4; ++j) {
                ta[j]     = f2bf(((const float*)&ra[i][0])[j]);
                ta[j + 4] = f2bf(((const float*)&ra[i][1])[j]);
                tb[j]     = f2bf(((const float*)&rb[i][0])[j]);
                tb[j + 4] = f2bf(((const float*)&rb[i][1])[j]);
            }
            *(ushort8*)&As[row][c8] = ta;
            *(ushort8*)&Bs[row][c8] = tb;
        }
    };

    const int lane = tid & 63;
    const int wid  = tid >> 6;
    const int wr = wid >> 1, wc = wid & 1;
    const int row0 = wr * 64, col0 = wc * 64;
    const int fr = lane & 15;
    const int fg = lane >> 4;

    floatx4 acc[4][4];
#pragma unroll
    for (int m = 0; m < 4; ++m)
#pragma unroll
        for (int n = 0; n < 4; ++n)
            acc[m][n] = (floatx4){0.f, 0.f, 0.f, 0.f};

    load_tile(0);
    for (int kt = 0; kt < NKT; ++kt) {
        if (kt) __syncthreads();
        store_tile();
        __syncthreads();
        if (kt + 1 < NKT) load_tile(kt + 1);
#pragma unroll
        for (int kk = 0; kk < 2; ++kk) {
            short8 af[4], bf8[4];
#pragma unroll
            for (int m = 0; m < 4; ++m)
                af[m] = *(const short8*)&As[row0 + m * 16 + fr][kk * 32 + fg * 8];
#pragma unroll
            for (int n = 0; n < 4; ++n)
                bf8[n] = *(const short8*)&Bs[col0 + n * 16 + fr][kk * 32 + fg * 8];
#pragma unroll
            for (int m = 0; m < 4; ++m)
#pragma unroll
                for (int n = 0; n < 4; ++n)
                    acc[m][n] = __builtin_amdgcn_mfma_f32_16x16x32_bf16(
                        af[m], bf8[n], acc[m][n], 0, 0, 0);
        }
    }

#pragma unroll
    for (int n = 0; n < 4; ++n) {
        int col = bcol + col0 + n * 16 + fr;
        if (col >= CLS) continue;
        float bv = bias[col];
#pragma unroll
        for (int m = 0; m < 4; ++m) {
#pragma unroll
            for (int j = 0; j < 4; ++j) {
                int row = brow + row0 + m * 16 + fg * 4 + j;
                float z = acc[m][n][j] + bv;
                float s = fmaxf(z, 0.f) + log1pf(expf(-fabsf(z)));
                out[(size_t)row * CLS + col] = s + 1.f;
            }
        }
    }
}

// ---------------- DS combine (per-row) ----------------

__global__ __launch_bounds__(256)
void ds_combine(const float* __restrict__ AX, const float* __restrict__ AY,
                float* __restrict__ out)
{
    const int row = blockIdx.x;
    const int t = threadIdx.x;
    const float* ax = AX + (size_t)row * CLS;
    const float* ay = AY + (size_t)row * CLS;

    float4 vx = make_float4(0.f, 0.f, 0.f, 0.f);
    float4 vy = make_float4(0.f, 0.f, 0.f, 0.f);
    const bool act = t < (CLS / 4);
    if (act) {
        vx = *(const float4*)(ax + t * 4);
        vy = *(const float4*)(ay + t * 4);
    }
    float sx = 0.f, sy = 0.f, sp = 0.f;
    if (act) {
        const float* px = (const float*)&vx;
        const float* py = (const float*)&vy;
#pragma unroll
        for (int j = 0; j < 4; ++j) {
            sx += px[j]; sy += py[j];
            sp += (px[j] - 1.f) * (py[j] - 1.f);
        }
    }
#pragma unroll
    for (int off = 32; off > 0; off >>= 1) {
        sx += __shfl_down(sx, off);
        sy += __shfl_down(sy, off);
        sp += __shfl_down(sp, off);
    }
    __shared__ float red[3][4];
    const int lane = t & 63, w = t >> 6;
    if (lane == 0) { red[0][w] = sx; red[1][w] = sy; red[2][w] = sp; }
    __syncthreads();
    const float S1 = red[0][0] + red[0][1] + red[0][2] + red[0][3];
    const float S2 = red[1][0] + red[1][1] + red[1][2] + red[1][3];
    const float P  = red[2][0] + red[2][1] + red[2][2] + red[2][3];

    const float i1 = 1.f / S1, i2 = 1.f / S2;
    const float u1 = (float)CLS * i1, u2 = (float)CLS * i2;
    const float sb1 = (S1 - (float)CLS) * i1;
    const float sb2 = (S2 - (float)CLS) * i2;
    const float conf = sb1 * sb2 - P * i1 * i2;
    const float denom = 1.f - conf;
    const float idenom = 1.f / denom;
    const float Sa = (float)CLS * denom / (u1 * u2);

    if (act) {
        float4 vo;
        const float* px = (const float*)&vx;
        const float* py = (const float*)&vy;
        float* po = (float*)&vo;
#pragma unroll
        for (int j = 0; j < 4; ++j) {
            float b1 = (px[j] - 1.f) * i1;
            float b2 = (py[j] - 1.f) * i2;
            float ba = (b1 * b2 + b1 * u2 + b2 * u1) * idenom;
            po[j] = ba * Sa + 1.f;
        }
        *(float4*)(out + (size_t)row * CLS + t * 4) = vo;
    }
}

extern "C" void kernel_launch(void* const* d_in, const int* in_sizes, int n_in,
                              void* d_out, int out_size, void* d_ws, size_t ws_size,
                              hipStream_t stream) {
    const float* x  = (const float*)d_in[0];
    const float* y  = (const float*)d_in[1];
    const float* Wx = (const float*)d_in[2];
    const float* bx = (const float*)d_in[3];
    const float* Wy = (const float*)d_in[4];
    const float* by = (const float*)d_in[5];
    float* out = (float*)d_out;
    float* ax = out + (size_t)BATCH_N * CLS;
    float* ay = ax  + (size_t)BATCH_N * CLS;

    const size_t SZ_X = (size_t)BATCH_N * K_DIM;      // 16.78M
    const size_t SZ_W = (size_t)NPAD * K_DIM;         // 2.10M
    const size_t need = (2 * SZ_X + 2 * SZ_W) * sizeof(ushort); // 75.5 MB

    if (ws_size >= need) {
        ushort* xb  = (ushort*)d_ws;
        ushort* yb  = xb + SZ_X;
        ushort* wxb = yb + SZ_X;
        ushort* wyb = wxb + SZ_W;

        convert_xy<<<dim3(SZ_X / (256 * 8), 1, 2), 256, 0, stream>>>(x, y, xb, yb);
        convert_w <<<dim3(SZ_W / (256 * 8), 1, 2), 256, 0, stream>>>(Wx, Wy, wxb, wyb);
        gemm_bf16<<<dim3(NPAD / BN, BATCH_N / BM, 2), 256, 0, stream>>>(
            xb, yb, wxb, wyb, bx, by, ax, ay);
    } else {
        gemm_alpha<<<dim3((CLS + BN - 1) / BN, BATCH_N / BM, 2), 256, 0, stream>>>(
            x, y, Wx, Wy, bx, by, ax, ay);
    }
    ds_combine<<<BATCH_N, 256, 0, stream>>>(ax, ay, out);
}

// Round 3
// 156.637 us; speedup vs baseline: 1.3493x; 1.2554x over previous
//
#include <hip/hip_runtime.h>
#include <hip/hip_bf16.h>
#include <math.h>

#define BATCH_N 8192
#define K_DIM   2048
#define CLS     1000
#define NPAD    1024

typedef __attribute__((ext_vector_type(8))) short short8;
typedef __attribute__((ext_vector_type(8))) unsigned short ushort8;
typedef __attribute__((ext_vector_type(4))) float floatx4;

static __device__ __forceinline__ ushort f2bf(float f) {
    union { float f; unsigned u; } v; v.f = f;
    unsigned u = v.u;
    return (ushort)((u + 0x7FFFu + ((u >> 16) & 1u)) >> 16); // RNE
}

static __device__ __forceinline__ void gld_lds16(const void* g, void* l) {
    __builtin_amdgcn_global_load_lds(
        (const __attribute__((address_space(1))) void*)g,
        (__attribute__((address_space(3))) void*)l, 16, 0, 0);
}

// fast softplus: 2 HW transcendentals, abs err ~1e-5
static __device__ __forceinline__ float softplus_fast(float z) {
    return fmaxf(z, 0.f) + __logf(1.f + __expf(-fabsf(z)));
}

// ---------------- pre-convert to bf16 in workspace ----------------

__global__ __launch_bounds__(256)
void convert_xy(const float* __restrict__ x, const float* __restrict__ y,
                ushort* __restrict__ ox, ushort* __restrict__ oy)
{
    const float* src = blockIdx.z ? y : x;
    ushort* dst      = blockIdx.z ? oy : ox;
    size_t e = ((size_t)blockIdx.x * 256 + threadIdx.x) * 8;
    float4 a = *(const float4*)(src + e);
    float4 b = *(const float4*)(src + e + 4);
    ushort8 t;
#pragma unroll
    for (int j = 0; j < 4; ++j) {
        t[j]     = f2bf(((const float*)&a)[j]);
        t[j + 4] = f2bf(((const float*)&b)[j]);
    }
    *(ushort8*)(dst + e) = t;
}

__global__ __launch_bounds__(256)
void convert_w(const float* __restrict__ wx, const float* __restrict__ wy,
               ushort* __restrict__ owx, ushort* __restrict__ owy)
{
    const float* src = blockIdx.z ? wy : wx;
    ushort* dst      = blockIdx.z ? owy : owx;
    size_t e = ((size_t)blockIdx.x * 256 + threadIdx.x) * 8;
    int row = (int)(e >> 11);
    ushort8 t = (ushort8)0;
    if (row < CLS) {
        float4 a = *(const float4*)(src + e);
        float4 b = *(const float4*)(src + e + 4);
#pragma unroll
        for (int j = 0; j < 4; ++j) {
            t[j]     = f2bf(((const float*)&a)[j]);
            t[j + 4] = f2bf(((const float*)&b)[j]);
        }
    }
    *(ushort8*)(dst + e) = t;
}

// ------------- bf16 GEMM: 128x128 tile, BK=64, gld_lds + XOR swizzle --------
// LDS layout: linear [128][64] bf16, but element (row, colchunk c8) lives at
// physical colchunk c8 ^ (row&7). gld_lds writes linearly (base+lane*16B), so
// the SOURCE global address carries the inverse permutation (same XOR), and
// fragment reads apply the XOR. 16-way bank conflict -> 2-way (free).

constexpr int BM = 128, BN = 128, BK = 64;
constexpr int NKT = K_DIM / BK; // 32

__global__ __launch_bounds__(256)
void gemm_bf16(const ushort* __restrict__ Aa, const ushort* __restrict__ Ab,
               const ushort* __restrict__ Ba, const ushort* __restrict__ Bb,
               const float* __restrict__ biasa, const float* __restrict__ biasb,
               float* __restrict__ outa, float* __restrict__ outb)
{
    const ushort* A   = blockIdx.z ? Ab : Aa;
    const ushort* B   = blockIdx.z ? Bb : Ba;
    const float* bias = blockIdx.z ? biasb : biasa;
    float* out        = blockIdx.z ? outb : outa;

    __shared__ ushort As[BM * BK];
    __shared__ ushort Bs[BN * BK];

    const int tid  = threadIdx.x;
    const int lane = tid & 63;
    const int wid  = tid >> 6;
    const int brow = blockIdx.y * BM;
    const int bcol = blockIdx.x * BN;

    // staging geometry: instr i covers rows [i*32+wid*8, +8), lane>>3 = row-in-group,
    // lane&7 = 16B col chunk. row&7 == lane>>3 here, so swizzled source col chunk:
    const int r8   = lane >> 3;                       // row within 8-row group = row&7
    const int csw  = (((lane & 7) ^ r8) << 3);        // swizzled col (elements)

    const int wr = wid >> 1, wc = wid & 1;            // 2x2 waves, 64x64 each
    const int row0 = wr * 64, col0 = wc * 64;
    const int fr = lane & 15;
    const int fg = lane >> 4;
    const int frx8 = (fr & 7) << 3;                   // read-side XOR (elements)

    floatx4 acc[4][4];
#pragma unroll
    for (int m = 0; m < 4; ++m)
#pragma unroll
        for (int n = 0; n < 4; ++n)
            acc[m][n] = (floatx4){0.f, 0.f, 0.f, 0.f};

    for (int kt = 0; kt < NKT; ++kt) {
        const int kbase = kt * BK;
#pragma unroll
        for (int i = 0; i < 4; ++i) {
            int row = i * 32 + wid * 8 + r8;
            gld_lds16(A + (size_t)(brow + row) * K_DIM + kbase + csw,
                      As + i * 2048 + wid * 512);
            gld_lds16(B + (size_t)(bcol + row) * K_DIM + kbase + csw,
                      Bs + i * 2048 + wid * 512);
        }
        __syncthreads();   // drains vmcnt -> tiles resident
#pragma unroll
        for (int kk = 0; kk < 2; ++kk) {
            short8 af[4], bf8[4];
#pragma unroll
            for (int m = 0; m < 4; ++m)
                af[m] = *(const short8*)&As[(row0 + m * 16 + fr) * BK +
                                            ((kk * 32 + fg * 8) ^ frx8)];
#pragma unroll
            for (int n = 0; n < 4; ++n)
                bf8[n] = *(const short8*)&Bs[(col0 + n * 16 + fr) * BK +
                                             ((kk * 32 + fg * 8) ^ frx8)];
#pragma unroll
            for (int m = 0; m < 4; ++m)
#pragma unroll
                for (int n = 0; n < 4; ++n)
                    acc[m][n] = __builtin_amdgcn_mfma_f32_16x16x32_bf16(
                        af[m], bf8[n], acc[m][n], 0, 0, 0);
        }
        __syncthreads();
    }

#pragma unroll
    for (int n = 0; n < 4; ++n) {
        int col = bcol + col0 + n * 16 + fr;
        if (col >= CLS) continue;
        float bv = bias[col];
#pragma unroll
        for (int m = 0; m < 4; ++m) {
#pragma unroll
            for (int j = 0; j < 4; ++j) {
                int row = brow + row0 + m * 16 + fg * 4 + j;
                float z = acc[m][n][j] + bv;
                out[(size_t)row * CLS + col] = softplus_fast(z) + 1.f;
            }
        }
    }
}

// ---------------- fallback path (no workspace): fused fp32->bf16 ------------

constexpr int LDP = BK + 8;

__global__ __launch_bounds__(256, 2)
void gemm_alpha(const float* __restrict__ Xa, const float* __restrict__ Xb,
                const float* __restrict__ Wa, const float* __restrict__ Wb,
                const float* __restrict__ ba, const float* __restrict__ bb,
                float* __restrict__ outa, float* __restrict__ outb)
{
    const float* X   = blockIdx.z ? Xb : Xa;
    const float* W   = blockIdx.z ? Wb : Wa;
    const float* bias= blockIdx.z ? bb : ba;
    float* out       = blockIdx.z ? outb : outa;

    __shared__ ushort As[BM][LDP];
    __shared__ ushort Bs[BN][LDP];

    const int tid  = threadIdx.x;
    const int brow = blockIdx.y * BM;
    const int bcol = blockIdx.x * BN;

    float4 ra[4][2], rb[4][2];

    auto load_tile = [&](int kt) {
        const int kbase = kt * BK;
#pragma unroll
        for (int i = 0; i < 4; ++i) {
            int idx = tid + i * 256;
            int row = idx >> 3;
            int c8  = (idx & 7) << 3;
            const float* pA = X + (size_t)(brow + row) * K_DIM + kbase + c8;
            ra[i][0] = *(const float4*)pA;
            ra[i][1] = *(const float4*)(pA + 4);
            int wrow = bcol + row; if (wrow >= CLS) wrow = CLS - 1;
            const float* pB = W + (size_t)wrow * K_DIM + kbase + c8;
            rb[i][0] = *(const float4*)pB;
            rb[i][1] = *(const float4*)(pB + 4);
        }
    };

    auto store_tile = [&]() {
#pragma unroll
        for (int i = 0; i < 4; ++i) {
            int idx = tid + i * 256;
            int row = idx >> 3;
            int c8  = (idx & 7) << 3;
            ushort8 ta, tb;
#pragma unroll
            for (int j = 0; j < 4; ++j) {
                ta[j]     = f2bf(((const float*)&ra[i][0])[j]);
                ta[j + 4] = f2bf(((const float*)&ra[i][1])[j]);
                tb[j]     = f2bf(((const float*)&rb[i][0])[j]);
                tb[j + 4] = f2bf(((const float*)&rb[i][1])[j]);
            }
            *(ushort8*)&As[row][c8] = ta;
            *(ushort8*)&Bs[row][c8] = tb;
        }
    };

    const int lane = tid & 63;
    const int wid  = tid >> 6;
    const int wr = wid >> 1, wc = wid & 1;
    const int row0 = wr * 64, col0 = wc * 64;
    const int fr = lane & 15;
    const int fg = lane >> 4;

    floatx4 acc[4][4];
#pragma unroll
    for (int m = 0; m < 4; ++m)
#pragma unroll
        for (int n = 0; n < 4; ++n)
            acc[m][n] = (floatx4){0.f, 0.f, 0.f, 0.f};

    load_tile(0);
    for (int kt = 0; kt < NKT; ++kt) {
        if (kt) __syncthreads();
        store_tile();
        __syncthreads();
        if (kt + 1 < NKT) load_tile(kt + 1);
#pragma unroll
        for (int kk = 0; kk < 2; ++kk) {
            short8 af[4], bf8[4];
#pragma unroll
            for (int m = 0; m < 4; ++m)
                af[m] = *(const short8*)&As[row0 + m * 16 + fr][kk * 32 + fg * 8];
#pragma unroll
            for (int n = 0; n < 4; ++n)
                bf8[n] = *(const short8*)&Bs[col0 + n * 16 + fr][kk * 32 + fg * 8];
#pragma unroll
            for (int m = 0; m < 4; ++m)
#pragma unroll
                for (int n = 0; n < 4; ++n)
                    acc[m][n] = __builtin_amdgcn_mfma_f32_16x16x32_bf16(
                        af[m], bf8[n], acc[m][n], 0, 0, 0);
        }
    }

#pragma unroll
    for (int n = 0; n < 4; ++n) {
        int col = bcol + col0 + n * 16 + fr;
        if (col >= CLS) continue;
        float bv = bias[col];
#pragma unroll
        for (int m = 0; m < 4; ++m) {
#pragma unroll
            for (int j = 0; j < 4; ++j) {
                int row = brow + row0 + m * 16 + fg * 4 + j;
                float z = acc[m][n][j] + bv;
                out[(size_t)row * CLS + col] = softplus_fast(z) + 1.f;
            }
        }
    }
}

// ---------------- DS combine (per-row) ----------------

__global__ __launch_bounds__(256)
void ds_combine(const float* __restrict__ AX, const float* __restrict__ AY,
                float* __restrict__ out)
{
    const int row = blockIdx.x;
    const int t = threadIdx.x;
    const float* ax = AX + (size_t)row * CLS;
    const float* ay = AY + (size_t)row * CLS;

    float4 vx = make_float4(0.f, 0.f, 0.f, 0.f);
    float4 vy = make_float4(0.f, 0.f, 0.f, 0.f);
    const bool act = t < (CLS / 4);
    if (act) {
        vx = *(const float4*)(ax + t * 4);
        vy = *(const float4*)(ay + t * 4);
    }
    float sx = 0.f, sy = 0.f, sp = 0.f;
    if (act) {
        const float* px = (const float*)&vx;
        const float* py = (const float*)&vy;
#pragma unroll
        for (int j = 0; j < 4; ++j) {
            sx += px[j]; sy += py[j];
            sp += (px[j] - 1.f) * (py[j] - 1.f);
        }
    }
#pragma unroll
    for (int off = 32; off > 0; off >>= 1) {
        sx += __shfl_down(sx, off);
        sy += __shfl_down(sy, off);
        sp += __shfl_down(sp, off);
    }
    __shared__ float red[3][4];
    const int lane = t & 63, w = t >> 6;
    if (lane == 0) { red[0][w] = sx; red[1][w] = sy; red[2][w] = sp; }
    __syncthreads();
    const float S1 = red[0][0] + red[0][1] + red[0][2] + red[0][3];
    const float S2 = red[1][0] + red[1][1] + red[1][2] + red[1][3];
    const float P  = red[2][0] + red[2][1] + red[2][2] + red[2][3];

    const float i1 = 1.f / S1, i2 = 1.f / S2;
    const float u1 = (float)CLS * i1, u2 = (float)CLS * i2;
    const float sb1 = (S1 - (float)CLS) * i1;
    const float sb2 = (S2 - (float)CLS) * i2;
    const float conf = sb1 * sb2 - P * i1 * i2;
    const float denom = 1.f - conf;
    const float idenom = 1.f / denom;
    const float Sa = (float)CLS * denom / (u1 * u2);

    if (act) {
        float4 vo;
        const float* px = (const float*)&vx;
        const float* py = (const float*)&vy;
        float* po = (float*)&vo;
#pragma unroll
        for (int j = 0; j < 4; ++j) {
            float b1 = (px[j] - 1.f) * i1;
            float b2 = (py[j] - 1.f) * i2;
            float ba = (b1 * b2 + b1 * u2 + b2 * u1) * idenom;
            po[j] = ba * Sa + 1.f;
        }
        *(float4*)(out + (size_t)row * CLS + t * 4) = vo;
    }
}

extern "C" void kernel_launch(void* const* d_in, const int* in_sizes, int n_in,
                              void* d_out, int out_size, void* d_ws, size_t ws_size,
                              hipStream_t stream) {
    const float* x  = (const float*)d_in[0];
    const float* y  = (const float*)d_in[1];
    const float* Wx = (const float*)d_in[2];
    const float* bx = (const float*)d_in[3];
    const float* Wy = (const float*)d_in[4];
    const float* by = (const float*)d_in[5];
    float* out = (float*)d_out;
    float* ax = out + (size_t)BATCH_N * CLS;
    float* ay = ax  + (size_t)BATCH_N * CLS;

    const size_t SZ_X = (size_t)BATCH_N * K_DIM;
    const size_t SZ_W = (size_t)NPAD * K_DIM;
    const size_t need = (2 * SZ_X + 2 * SZ_W) * sizeof(ushort); // 75.5 MB

    if (ws_size >= need) {
        ushort* xb  = (ushort*)d_ws;
        ushort* yb  = xb + SZ_X;
        ushort* wxb = yb + SZ_X;
        ushort* wyb = wxb + SZ_W;

        convert_xy<<<dim3(SZ_X / (256 * 8), 1, 2), 256, 0, stream>>>(x, y, xb, yb);
        convert_w <<<dim3(SZ_W / (256 * 8), 1, 2), 256, 0, stream>>>(Wx, Wy, wxb, wyb);
        gemm_bf16<<<dim3(NPAD / BN, BATCH_N / BM, 2), 256, 0, stream>>>(
            xb, yb, wxb, wyb, bx, by, ax, ay);
    } else {
        gemm_alpha<<<dim3((CLS + BN - 1) / BN, BATCH_N / BM, 2), 256, 0, stream>>>(
            x, y, Wx, Wy, bx, by, ax, ay);
    }
    ds_combine<<<BATCH_N, 256, 0, stream>>>(ax, ay, out);
}

// Round 4
// 153.857 us; speedup vs baseline: 1.3737x; 1.0181x over previous
//
#include <hip/hip_runtime.h>
#include <hip/hip_bf16.h>
#include <math.h>

#define BATCH_N 8192
#define K_DIM   2048
#define CLS     1000
#define NPAD    1024

typedef __attribute__((ext_vector_type(8))) short short8;
typedef __attribute__((ext_vector_type(8))) unsigned short ushort8;
typedef __attribute__((ext_vector_type(4))) float floatx4;

static __device__ __forceinline__ ushort f2bf(float f) {
    union { float f; unsigned u; } v; v.f = f;
    unsigned u = v.u;
    return (ushort)((u + 0x7FFFu + ((u >> 16) & 1u)) >> 16); // RNE
}

static __device__ __forceinline__ void gld_lds16(const void* g, void* l) {
    __builtin_amdgcn_global_load_lds(
        (const __attribute__((address_space(1))) void*)g,
        (__attribute__((address_space(3))) void*)l, 16, 0, 0);
}

static __device__ __forceinline__ float softplus_fast(float z) {
    return fmaxf(z, 0.f) + __logf(1.f + __expf(-fabsf(z)));
}

// ---------------- single-pass convert: x,y -> bf16; W -> bf16 padded --------
// block ranges: [0,8192) x | [8192,16384) y | [16384,17408) Wx | [17408,18432) Wy
__global__ __launch_bounds__(256)
void convert_all(const float* __restrict__ x, const float* __restrict__ y,
                 const float* __restrict__ wx, const float* __restrict__ wy,
                 ushort* __restrict__ xb, ushort* __restrict__ yb,
                 ushort* __restrict__ wxb, ushort* __restrict__ wyb)
{
    int b = blockIdx.x;
    const float* src; ushort* dst; bool isw = false;
    if (b < 8192)       { src = x;  dst = xb; }
    else if (b < 16384) { src = y;  dst = yb;  b -= 8192; }
    else if (b < 17408) { src = wx; dst = wxb; b -= 16384; isw = true; }
    else                { src = wy; dst = wyb; b -= 17408; isw = true; }
    size_t e = ((size_t)b * 256 + threadIdx.x) * 8;
    ushort8 t = (ushort8)0;
    if (!isw || (int)(e >> 11) < CLS) {
        float4 a = *(const float4*)(src + e);
        float4 c = *(const float4*)(src + e + 4);
#pragma unroll
        for (int j = 0; j < 4; ++j) {
            t[j]     = f2bf(((const float*)&a)[j]);
            t[j + 4] = f2bf(((const float*)&c)[j]);
        }
    }
    *(ushort8*)(dst + e) = t;
}

// ---------------- 256x256 bf16 GEMM, counted-vmcnt pipeline -----------------
// K-step 32; 4 rotating LDS slots (A+B) = 128 KiB; stage step s+2 while
// computing s; boundary = s_waitcnt vmcnt(4) + raw s_barrier (guarantees step
// s+1 resident: its 4 loads are older than the newest 4 outstanding).
// Slot layout: [128][64] ushort, logical (row 0..255, k 0..31) packed as
// p=row>>1, c8 = ((row&1)<<2)|(k>>3), physical chunk = c8 ^ (p&7)  (16B chunks).
// gld_lds dest is LINEAR (lane*16B); the XOR permutation is carried by the
// per-lane GLOBAL source address (rule 21: both-sides-or-neither).

constexpr int GBM = 256, GBN = 256, KS = 32;
constexpr int NSTEP = K_DIM / KS;       // 64
constexpr int SLOT  = 128 * 64;         // ushorts per slot (16 KiB)

__global__ __launch_bounds__(512, 2)
void gemm256(const ushort* __restrict__ Aa, const ushort* __restrict__ Ab,
             const ushort* __restrict__ Ba, const ushort* __restrict__ Bb,
             const float* __restrict__ biasa, const float* __restrict__ biasb,
             float* __restrict__ outa, float* __restrict__ outb)
{
    const ushort* A   = blockIdx.z ? Ab : Aa;
    const ushort* B   = blockIdx.z ? Bb : Ba;
    const float* bias = blockIdx.z ? biasb : biasa;
    float* out        = blockIdx.z ? outb : outa;

    __shared__ ushort As[4][SLOT];
    __shared__ ushort Bs[4][SLOT];

    const int tid  = threadIdx.x;
    const int lane = tid & 63;
    const int wid  = tid >> 6;            // 8 waves: 2 (wr) x 4 (wc)
    const int wr = wid >> 2, wc = wid & 3;
    const int fr = lane & 15, fg = lane >> 4;
    const int brow = blockIdx.y * GBM;
    const int bcol = blockIdx.x * GBN;

    // ---- staging precompute: 2 instrs each for A and B per step ----
    size_t aoff[2], boff[2];              // global element offsets (step 0)
    int    ldst[2];                       // LDS ushort offset within slot
#pragma unroll
    for (int i = 0; i < 2; ++i) {
        int q   = i * 512 + tid;          // 16B chunk index 0..1023
        int p   = q >> 3;
        int c8  = q & 7;
        int c8l = c8 ^ (p & 7);           // logical chunk this slot holds
        int r   = 2 * p + (c8l >> 2);     // logical row 0..255
        int k   = (c8l & 3) * 8;          // logical k 0..31
        aoff[i] = (size_t)(brow + r) * K_DIM + k;
        boff[i] = (size_t)(bcol + r) * K_DIM + k;
        ldst[i] = q * 8;                  // ushorts
    }

    // ---- fragment-read offsets (step-invariant; slot base rotates) ----
    int afoff[8], bfoff[4];
#pragma unroll
    for (int m = 0; m < 8; ++m) {
        int row = wr * 128 + m * 16 + fr;
        int p = row >> 1;
        int c = (((row & 1) << 2) | fg) ^ (p & 7);
        afoff[m] = (p * 8 + c) * 8;
    }
#pragma unroll
    for (int n = 0; n < 4; ++n) {
        int row = wc * 64 + n * 16 + fr;
        int p = row >> 1;
        int c = (((row & 1) << 2) | fg) ^ (p & 7);
        bfoff[n] = (p * 8 + c) * 8;
    }

    floatx4 acc[8][4];
#pragma unroll
    for (int m = 0; m < 8; ++m)
#pragma unroll
        for (int n = 0; n < 4; ++n)
            acc[m][n] = (floatx4){0.f, 0.f, 0.f, 0.f};

#define STAGE(s_, slot_)                                                      \
    {                                                                         \
        const size_t kb = (size_t)(s_) * KS;                                  \
        gld_lds16(A + aoff[0] + kb, &As[slot_][ldst[0]]);                     \
        gld_lds16(A + aoff[1] + kb, &As[slot_][ldst[1]]);                     \
        gld_lds16(B + boff[0] + kb, &Bs[slot_][ldst[0]]);                     \
        gld_lds16(B + boff[1] + kb, &Bs[slot_][ldst[1]]);                     \
    }

    // prologue: steps 0,1 in flight; wait oldest 4 (step 0) done
    STAGE(0, 0);
    STAGE(1, 1);
    asm volatile("s_waitcnt vmcnt(4)" ::: "memory");
    __builtin_amdgcn_s_barrier();
    __builtin_amdgcn_sched_barrier(0);

    for (int s = 0; s < NSTEP; ++s) {
        if (s + 2 < NSTEP) STAGE(s + 2, (s + 2) & 3);

        const ushort* as = &As[s & 3][0];
        const ushort* bs = &Bs[s & 3][0];
        short8 af[8], bf[4];
#pragma unroll
        for (int m = 0; m < 8; ++m) af[m] = *(const short8*)(as + afoff[m]);
#pragma unroll
        for (int n = 0; n < 4; ++n) bf[n] = *(const short8*)(bs + bfoff[n]);

        __builtin_amdgcn_s_setprio(1);
#pragma unroll
        for (int m = 0; m < 8; ++m)
#pragma unroll
            for (int n = 0; n < 4; ++n)
                acc[m][n] = __builtin_amdgcn_mfma_f32_16x16x32_bf16(
                    af[m], bf[n], acc[m][n], 0, 0, 0);
        __builtin_amdgcn_s_setprio(0);

        if (s < NSTEP - 1) {
            if (s + 2 < NSTEP) asm volatile("s_waitcnt vmcnt(4)" ::: "memory");
            else               asm volatile("s_waitcnt vmcnt(0)" ::: "memory");
            __builtin_amdgcn_s_barrier();
            __builtin_amdgcn_sched_barrier(0);
        }
    }
#undef STAGE

    // epilogue: alpha = softplus(z + bias) + 1, predicated on col < 1000
#pragma unroll
    for (int n = 0; n < 4; ++n) {
        int col = bcol + wc * 64 + n * 16 + fr;
        if (col >= CLS) continue;
        float bv = bias[col];
#pragma unroll
        for (int m = 0; m < 8; ++m) {
#pragma unroll
            for (int j = 0; j < 4; ++j) {
                int row = brow + wr * 128 + m * 16 + fg * 4 + j;
                float z = acc[m][n][j] + bv;
                out[(size_t)row * CLS + col] = softplus_fast(z) + 1.f;
            }
        }
    }
}

// ---------------- fallback path (no workspace): round-1 fused GEMM ----------

constexpr int FBM = 128, FBN = 128, FBK = 64;
constexpr int FNKT = K_DIM / FBK;
constexpr int LDP = FBK + 8;

__global__ __launch_bounds__(256, 2)
void gemm_alpha(const float* __restrict__ Xa, const float* __restrict__ Xb,
                const float* __restrict__ Wa, const float* __restrict__ Wb,
                const float* __restrict__ ba, const float* __restrict__ bb,
                float* __restrict__ outa, float* __restrict__ outb)
{
    const float* X   = blockIdx.z ? Xb : Xa;
    const float* W   = blockIdx.z ? Wb : Wa;
    const float* bias= blockIdx.z ? bb : ba;
    float* out       = blockIdx.z ? outb : outa;

    __shared__ ushort As[FBM][LDP];
    __shared__ ushort Bs[FBN][LDP];

    const int tid  = threadIdx.x;
    const int brow = blockIdx.y * FBM;
    const int bcol = blockIdx.x * FBN;

    float4 ra[4][2], rb[4][2];

    auto load_tile = [&](int kt) {
        const int kbase = kt * FBK;
#pragma unroll
        for (int i = 0; i < 4; ++i) {
            int idx = tid + i * 256;
            int row = idx >> 3;
            int c8  = (idx & 7) << 3;
            const float* pA = X + (size_t)(brow + row) * K_DIM + kbase + c8;
            ra[i][0] = *(const float4*)pA;
            ra[i][1] = *(const float4*)(pA + 4);
            int wrow = bcol + row; if (wrow >= CLS) wrow = CLS - 1;
            const float* pB = W + (size_t)wrow * K_DIM + kbase + c8;
            rb[i][0] = *(const float4*)pB;
            rb[i][1] = *(const float4*)(pB + 4);
        }
    };

    auto store_tile = [&]() {
#pragma unroll
        for (int i = 0; i < 4; ++i) {
            int idx = tid + i * 256;
            int row = idx >> 3;
            int c8  = (idx & 7) << 3;
            ushort8 ta, tb;
#pragma unroll
            for (int j = 0; j < 4; ++j) {
                ta[j]     = f2bf(((const float*)&ra[i][0])[j]);
                ta[j + 4] = f2bf(((const float*)&ra[i][1])[j]);
                tb[j]     = f2bf(((const float*)&rb[i][0])[j]);
                tb[j + 4] = f2bf(((const float*)&rb[i][1])[j]);
            }
            *(ushort8*)&As[row][c8] = ta;
            *(ushort8*)&Bs[row][c8] = tb;
        }
    };

    const int lane = tid & 63;
    const int wid  = tid >> 6;
    const int wr = wid >> 1, wc = wid & 1;
    const int row0 = wr * 64, col0 = wc * 64;
    const int fr = lane & 15;
    const int fg = lane >> 4;

    floatx4 acc[4][4];
#pragma unroll
    for (int m = 0; m < 4; ++m)
#pragma unroll
        for (int n = 0; n < 4; ++n)
            acc[m][n] = (floatx4){0.f, 0.f, 0.f, 0.f};

    load_tile(0);
    for (int kt = 0; kt < FNKT; ++kt) {
        if (kt) __syncthreads();
        store_tile();
        __syncthreads();
        if (kt + 1 < FNKT) load_tile(kt + 1);
#pragma unroll
        for (int kk = 0; kk < 2; ++kk) {
            short8 af[4], bf8[4];
#pragma unroll
            for (int m = 0; m < 4; ++m)
                af[m] = *(const short8*)&As[row0 + m * 16 + fr][kk * 32 + fg * 8];
#pragma unroll
            for (int n = 0; n < 4; ++n)
                bf8[n] = *(const short8*)&Bs[col0 + n * 16 + fr][kk * 32 + fg * 8];
#pragma unroll
            for (int m = 0; m < 4; ++m)
#pragma unroll
                for (int n = 0; n < 4; ++n)
                    acc[m][n] = __builtin_amdgcn_mfma_f32_16x16x32_bf16(
                        af[m], bf8[n], acc[m][n], 0, 0, 0);
        }
    }

#pragma unroll
    for (int n = 0; n < 4; ++n) {
        int col = bcol + col0 + n * 16 + fr;
        if (col >= CLS) continue;
        float bv = bias[col];
#pragma unroll
        for (int m = 0; m < 4; ++m) {
#pragma unroll
            for (int j = 0; j < 4; ++j) {
                int row = brow + row0 + m * 16 + fg * 4 + j;
                float z = acc[m][n][j] + bv;
                out[(size_t)row * CLS + col] = softplus_fast(z) + 1.f;
            }
        }
    }
}

// ---------------- DS combine: one wave per row, shuffle-xor reduce ----------

__global__ __launch_bounds__(256)
void ds_combine(const float* __restrict__ AX, const float* __restrict__ AY,
                float* __restrict__ out)
{
    const int row = blockIdx.x * 4 + (threadIdx.x >> 6);
    const int l = threadIdx.x & 63;
    const float* ax = AX + (size_t)row * CLS;
    const float* ay = AY + (size_t)row * CLS;

    float4 vx[4], vy[4];
    float sx = 0.f, sy = 0.f, sp = 0.f;
#pragma unroll
    for (int c = 0; c < 4; ++c) {
        int idx = l + c * 64;            // float4 index, 250 valid
        if (idx < CLS / 4) {
            vx[c] = *(const float4*)(ax + idx * 4);
            vy[c] = *(const float4*)(ay + idx * 4);
            const float* px = (const float*)&vx[c];
            const float* py = (const float*)&vy[c];
#pragma unroll
            for (int j = 0; j < 4; ++j) {
                sx += px[j]; sy += py[j];
                sp += (px[j] - 1.f) * (py[j] - 1.f);
            }
        }
    }
#pragma unroll
    for (int off = 1; off < 64; off <<= 1) {
        sx += __shfl_xor(sx, off);
        sy += __shfl_xor(sy, off);
        sp += __shfl_xor(sp, off);
    }
    const float S1 = sx, S2 = sy, P = sp;
    const float i1 = 1.f / S1, i2 = 1.f / S2;
    const float u1 = (float)CLS * i1, u2 = (float)CLS * i2;
    const float sb1 = (S1 - (float)CLS) * i1;
    const float sb2 = (S2 - (float)CLS) * i2;
    const float conf = sb1 * sb2 - P * i1 * i2;
    const float denom = 1.f - conf;
    const float idenom = 1.f / denom;
    const float Sa = (float)CLS * denom / (u1 * u2);

#pragma unroll
    for (int c = 0; c < 4; ++c) {
        int idx = l + c * 64;
        if (idx < CLS / 4) {
            float4 vo;
            const float* px = (const float*)&vx[c];
            const float* py = (const float*)&vy[c];
            float* po = (float*)&vo;
#pragma unroll
            for (int j = 0; j < 4; ++j) {
                float b1 = (px[j] - 1.f) * i1;
                float b2 = (py[j] - 1.f) * i2;
                float ba = (b1 * b2 + b1 * u2 + b2 * u1) * idenom;
                po[j] = ba * Sa + 1.f;
            }
            *(float4*)(out + (size_t)row * CLS + idx * 4) = vo;
        }
    }
}

extern "C" void kernel_launch(void* const* d_in, const int* in_sizes, int n_in,
                              void* d_out, int out_size, void* d_ws, size_t ws_size,
                              hipStream_t stream) {
    const float* x  = (const float*)d_in[0];
    const float* y  = (const float*)d_in[1];
    const float* Wx = (const float*)d_in[2];
    const float* bx = (const float*)d_in[3];
    const float* Wy = (const float*)d_in[4];
    const float* by = (const float*)d_in[5];
    float* out = (float*)d_out;
    float* ax = out + (size_t)BATCH_N * CLS;
    float* ay = ax  + (size_t)BATCH_N * CLS;

    const size_t SZ_X = (size_t)BATCH_N * K_DIM;
    const size_t SZ_W = (size_t)NPAD * K_DIM;
    const size_t need = (2 * SZ_X + 2 * SZ_W) * sizeof(ushort); // 75.5 MB

    if (ws_size >= need) {
        ushort* xb  = (ushort*)d_ws;
        ushort* yb  = xb + SZ_X;
        ushort* wxb = yb + SZ_X;
        ushort* wyb = wxb + SZ_W;

        convert_all<<<18432, 256, 0, stream>>>(x, y, Wx, Wy, xb, yb, wxb, wyb);
        gemm256<<<dim3(NPAD / GBN, BATCH_N / GBM, 2), 512, 0, stream>>>(
            xb, yb, wxb, wyb, bx, by, ax, ay);
    } else {
        gemm_alpha<<<dim3((CLS + FBN - 1) / FBN, BATCH_N / FBM, 2), 256, 0, stream>>>(
            x, y, Wx, Wy, bx, by, ax, ay);
    }
    ds_combine<<<BATCH_N / 4, 256, 0, stream>>>(ax, ay, out);
}

// Round 5
// 133.421 us; speedup vs baseline: 1.5841x; 1.1532x over previous
//
#include <hip/hip_runtime.h>
#include <hip/hip_bf16.h>
#include <math.h>

#define BATCH_N 8192
#define K_DIM   2048
#define CLS     1000
#define NPAD    1024

typedef __attribute__((ext_vector_type(8))) short short8;
typedef __attribute__((ext_vector_type(8))) unsigned short ushort8;
typedef __attribute__((ext_vector_type(4))) float floatx4;

static __device__ __forceinline__ ushort f2bf(float f) {
    union { float f; unsigned u; } v; v.f = f;
    unsigned u = v.u;
    return (ushort)((u + 0x7FFFu + ((u >> 16) & 1u)) >> 16); // RNE
}

static __device__ __forceinline__ void gld_lds16(const void* g, void* l) {
    __builtin_amdgcn_global_load_lds(
        (const __attribute__((address_space(1))) void*)g,
        (__attribute__((address_space(3))) void*)l, 16, 0, 0);
}

static __device__ __forceinline__ float softplus_fast(float z) {
    return fmaxf(z, 0.f) + __logf(1.f + __expf(-fabsf(z)));
}

// ---------------- single-pass convert: x,y -> bf16; W -> bf16 padded --------
__global__ __launch_bounds__(256)
void convert_all(const float* __restrict__ x, const float* __restrict__ y,
                 const float* __restrict__ wx, const float* __restrict__ wy,
                 ushort* __restrict__ xb, ushort* __restrict__ yb,
                 ushort* __restrict__ wxb, ushort* __restrict__ wyb)
{
    int b = blockIdx.x;
    const float* src; ushort* dst; bool isw = false;
    if (b < 8192)       { src = x;  dst = xb; }
    else if (b < 16384) { src = y;  dst = yb;  b -= 8192; }
    else if (b < 17408) { src = wx; dst = wxb; b -= 16384; isw = true; }
    else                { src = wy; dst = wyb; b -= 17408; isw = true; }
    size_t e = ((size_t)b * 256 + threadIdx.x) * 8;
    ushort8 t = (ushort8)0;
    if (!isw || (int)(e >> 11) < CLS) {
        float4 a = *(const float4*)(src + e);
        float4 c = *(const float4*)(src + e + 4);
#pragma unroll
        for (int j = 0; j < 4; ++j) {
            t[j]     = f2bf(((const float*)&a)[j]);
            t[j + 4] = f2bf(((const float*)&c)[j]);
        }
    }
    *(ushort8*)(dst + e) = t;
}

// ------------- 256x256 bf16 GEMM, 8-phase counted-vmcnt pipeline ------------
// 8 waves (2 wr x 4 wc), per-wave 128x64 output. BK=64, 2 LDS K-tile slots.
// Physical LDS per operand-slot: [256 rows][64 k] ushort with chunk-XOR
// swizzle (chunk c8 at row r holds k-range (c8^(r&7))*8; verified round 3,
// 0 bank conflicts). gld_lds dest linear; global source pre-swizzled.
// Half-tiles (staged 2 gld_lds each, one per phase):
//   A half h = rows with (r>>6)&1 == h  (read only in phase q0 (h=0)/q2 (h=1))
//   B half h = rows with (r>>5)&1 == h  (read only in phase q0 (h=0)/q1 (h=1))
// Stage during tile t: q0:B1(t+1) q1:A1(t+1) q2:A0(t+2) q3:B0(t+2).
// Waits: vmcnt(6) before the barrier at q0-end and q3-end (tail: 6/2, 0/-).
// Every half-tile is drained >=1 phase before first read; WAR overwrites are
// >=2 barriers after last read of the old data.

constexpr int NT = K_DIM / 64;   // 32 K-tiles

#define BARX __builtin_amdgcn_s_barrier()
#define LGKM0 asm volatile("s_waitcnt lgkmcnt(0)" ::: "memory")
#define VMW(n) asm volatile("s_waitcnt vmcnt(" #n ")" ::: "memory")
#define PRIO1 __builtin_amdgcn_s_setprio(1)
#define PRIO0 __builtin_amdgcn_s_setprio(0)

#define STAGE_A(h, sl, t_) {                                                  \
    const size_t kb_ = (size_t)(t_) * 64;                                     \
    gld_lds16(A + aofs_g[0] + (h) * 64 * K_DIM + kb_,                         \
              &As[sl][aofs_l[0] + (h) * 4096]);                               \
    gld_lds16(A + aofs_g[1] + (h) * 64 * K_DIM + kb_,                         \
              &As[sl][aofs_l[1] + (h) * 4096]); }
#define STAGE_B(h, sl, t_) {                                                  \
    const size_t kb_ = (size_t)(t_) * 64;                                     \
    gld_lds16(B + bofs_g[0] + (h) * 32 * K_DIM + kb_,                         \
              &Bs[sl][bofs_l[0] + (h) * 2048]);                               \
    gld_lds16(B + bofs_g[1] + (h) * 32 * K_DIM + kb_,                         \
              &Bs[sl][bofs_l[1] + (h) * 2048]); }

#define LDA(mh) {                                                             \
    const ushort* p_ = asl + wr * 8192 + (mh) * 4096;                         \
    a[0][0] = *(const short8*)(p_ + e0);        a[0][1] = *(const short8*)(p_ + e1); \
    a[1][0] = *(const short8*)(p_ + 1024 + e0); a[1][1] = *(const short8*)(p_ + 1024 + e1); \
    a[2][0] = *(const short8*)(p_ + 2048 + e0); a[2][1] = *(const short8*)(p_ + 2048 + e1); \
    a[3][0] = *(const short8*)(p_ + 3072 + e0); a[3][1] = *(const short8*)(p_ + 3072 + e1); }
#define LDB(nh, bb) {                                                         \
    const ushort* p_ = bsl + wc * 4096 + (nh) * 2048;                         \
    bb[0][0] = *(const short8*)(p_ + e0);        bb[0][1] = *(const short8*)(p_ + e1); \
    bb[1][0] = *(const short8*)(p_ + 1024 + e0); bb[1][1] = *(const short8*)(p_ + 1024 + e1); }

#define MM1(mh, nh, i, j, kk, bb)                                             \
    acc[(mh)*4+(i)][(nh)*2+(j)] = __builtin_amdgcn_mfma_f32_16x16x32_bf16(    \
        a[i][kk], bb[j][kk], acc[(mh)*4+(i)][(nh)*2+(j)], 0, 0, 0);
#define MQ(mh, nh, bb)                                                        \
    MM1(mh,nh,0,0,0,bb) MM1(mh,nh,0,1,0,bb) MM1(mh,nh,1,0,0,bb) MM1(mh,nh,1,1,0,bb) \
    MM1(mh,nh,2,0,0,bb) MM1(mh,nh,2,1,0,bb) MM1(mh,nh,3,0,0,bb) MM1(mh,nh,3,1,0,bb) \
    MM1(mh,nh,0,0,1,bb) MM1(mh,nh,0,1,1,bb) MM1(mh,nh,1,0,1,bb) MM1(mh,nh,1,1,1,bb) \
    MM1(mh,nh,2,0,1,bb) MM1(mh,nh,2,1,1,bb) MM1(mh,nh,3,0,1,bb) MM1(mh,nh,3,1,1,bb)

__global__ __launch_bounds__(512, 2)
void gemm8p(const ushort* __restrict__ Aa, const ushort* __restrict__ Ab,
            const ushort* __restrict__ Ba, const ushort* __restrict__ Bb,
            const float* __restrict__ biasa, const float* __restrict__ biasb,
            float* __restrict__ outa, float* __restrict__ outb)
{
    // bijective XCD swizzle over the 256-block grid (256 % 8 == 0)
    int flat = blockIdx.x + 4 * (blockIdx.y + 32 * blockIdx.z);
    int sw   = (flat & 7) * 32 + (flat >> 3);
    const int bx = sw & 3, by = (sw >> 2) & 31, bz = sw >> 7;

    const ushort* A   = bz ? Ab : Aa;
    const ushort* B   = bz ? Bb : Ba;
    const float* bias = bz ? biasb : biasa;
    float* out        = bz ? outb : outa;

    __shared__ ushort As[2][256 * 64];
    __shared__ ushort Bs[2][256 * 64];

    const int tid  = threadIdx.x;
    const int lane = tid & 63;
    const int wid  = tid >> 6;            // 8 waves: wr in {0,1}, wc in {0..3}
    const int wr = wid >> 2, wc = wid & 3;
    const int fr = lane & 15, fg = lane >> 4;
    const int frx8 = (fr & 7) << 3;
    const int brow = by * 256;
    const int bcol = bx * 256;

    // staging precompute (half h=0; h adds 64 (A) / 32 (B) rows)
    int    aofs_l[2], bofs_l[2];
    size_t aofs_g[2], bofs_g[2];
#pragma unroll
    for (int i = 0; i < 2; ++i) {
        int q = i * 512 + tid, rr = q >> 3, c8 = q & 7, c8l = c8 ^ (rr & 7);
        int ra = (rr >> 6) * 128 + (rr & 63);
        int rb = (rr >> 5) * 64  + (rr & 31);
        aofs_l[i] = ra * 64 + c8 * 8;
        bofs_l[i] = rb * 64 + c8 * 8;
        aofs_g[i] = (size_t)(brow + ra) * K_DIM + c8l * 8;
        bofs_g[i] = (size_t)(bcol + rb) * K_DIM + c8l * 8;
    }

    // fragment-read column terms (kk=0 / kk=1), swizzled
    const int e0 = fr * 64 + ((fg * 8) ^ frx8);
    const int e1 = fr * 64 + ((32 + fg * 8) ^ frx8);

    floatx4 acc[8][4];
#pragma unroll
    for (int m = 0; m < 8; ++m)
#pragma unroll
        for (int n = 0; n < 4; ++n)
            acc[m][n] = (floatx4){0.f, 0.f, 0.f, 0.f};

    // prologue: A0(0) B0(0) B1(0) A1(0) A0(1) B0(1); drain first 3 pairs
    STAGE_A(0, 0, 0) STAGE_B(0, 0, 0) STAGE_B(1, 0, 0) STAGE_A(1, 0, 0)
    STAGE_A(0, 1, 1) STAGE_B(0, 1, 1)
    VMW(6); BARX;

    short8 a[4][2], bl[2][2], bh[2][2];

#pragma unroll 1
    for (int t = 0; t < NT - 2; ++t) {
        const int sl = t & 1, sl1 = sl ^ 1;
        const ushort* asl = &As[sl][0];
        const ushort* bsl = &Bs[sl][0];
        // q0: read A0+B0, stage B1(t+1)
        LDA(0) LDB(0, bl)
        STAGE_B(1, sl1, t + 1)
        BARX; LGKM0;
        PRIO1; MQ(0, 0, bl) PRIO0;
        VMW(6); BARX;
        // q1: read B1, stage A1(t+1)
        LDB(1, bh)
        STAGE_A(1, sl1, t + 1)
        BARX; LGKM0;
        PRIO1; MQ(0, 1, bh) PRIO0;
        BARX;
        // q2: read A1, stage A0(t+2)
        LDA(1)
        STAGE_A(0, sl, t + 2)
        BARX; LGKM0;
        PRIO1; MQ(1, 1, bh) PRIO0;
        BARX;
        // q3: (B0 still in regs), stage B0(t+2)
        STAGE_B(0, sl, t + 2)
        BARX; LGKM0;
        PRIO1; MQ(1, 0, bl) PRIO0;
        VMW(6); BARX;
    }
    {   // t = NT-2: no t+2 stages; waits 6 then 2
        const int sl = (NT - 2) & 1, sl1 = sl ^ 1;
        const ushort* asl = &As[sl][0];
        const ushort* bsl = &Bs[sl][0];
        LDA(0) LDB(0, bl)
        STAGE_B(1, sl1, NT - 1)
        BARX; LGKM0; PRIO1; MQ(0, 0, bl) PRIO0; VMW(6); BARX;
        LDB(1, bh)
        STAGE_A(1, sl1, NT - 1)
        BARX; LGKM0; PRIO1; MQ(0, 1, bh) PRIO0; BARX;
        LDA(1)
        BARX; LGKM0; PRIO1; MQ(1, 1, bh) PRIO0; BARX;
        BARX; LGKM0; PRIO1; MQ(1, 0, bl) PRIO0; VMW(2); BARX;
    }
    {   // t = NT-1: no stages; drain rest
        const int sl = (NT - 1) & 1;
        const ushort* asl = &As[sl][0];
        const ushort* bsl = &Bs[sl][0];
        LDA(0) LDB(0, bl)
        BARX; LGKM0; PRIO1; MQ(0, 0, bl) PRIO0; VMW(0); BARX;
        LDB(1, bh)
        BARX; LGKM0; PRIO1; MQ(0, 1, bh) PRIO0; BARX;
        LDA(1)
        BARX; LGKM0; PRIO1; MQ(1, 1, bh) PRIO0; BARX;
        LGKM0; PRIO1; MQ(1, 0, bl) PRIO0;
    }

    // epilogue: alpha = softplus(z + bias) + 1, predicated on col < 1000
#pragma unroll
    for (int n = 0; n < 4; ++n) {
        int col = bcol + wc * 64 + n * 16 + fr;
        if (col >= CLS) continue;
        float bv = bias[col];
#pragma unroll
        for (int m = 0; m < 8; ++m) {
#pragma unroll
            for (int j = 0; j < 4; ++j) {
                int row = brow + wr * 128 + m * 16 + fg * 4 + j;
                float z = acc[m][n][j] + bv;
                out[(size_t)row * CLS + col] = softplus_fast(z) + 1.f;
            }
        }
    }
}

// ---------------- fallback path (no workspace): fused fp32->bf16 ------------

constexpr int FBM = 128, FBN = 128, FBK = 64;
constexpr int FNKT = K_DIM / FBK;
constexpr int LDP = FBK + 8;

__global__ __launch_bounds__(256, 2)
void gemm_alpha(const float* __restrict__ Xa, const float* __restrict__ Xb,
                const float* __restrict__ Wa, const float* __restrict__ Wb,
                const float* __restrict__ ba, const float* __restrict__ bb,
                float* __restrict__ outa, float* __restrict__ outb)
{
    const float* X   = blockIdx.z ? Xb : Xa;
    const float* W   = blockIdx.z ? Wb : Wa;
    const float* bias= blockIdx.z ? bb : ba;
    float* out       = blockIdx.z ? outb : outa;

    __shared__ ushort As[FBM][LDP];
    __shared__ ushort Bs[FBN][LDP];

    const int tid  = threadIdx.x;
    const int brow = blockIdx.y * FBM;
    const int bcol = blockIdx.x * FBN;

    float4 ra[4][2], rb[4][2];

    auto load_tile = [&](int kt) {
        const int kbase = kt * FBK;
#pragma unroll
        for (int i = 0; i < 4; ++i) {
            int idx = tid + i * 256;
            int row = idx >> 3;
            int c8  = (idx & 7) << 3;
            const float* pA = X + (size_t)(brow + row) * K_DIM + kbase + c8;
            ra[i][0] = *(const float4*)pA;
            ra[i][1] = *(const float4*)(pA + 4);
            int wrow = bcol + row; if (wrow >= CLS) wrow = CLS - 1;
            const float* pB = W + (size_t)wrow * K_DIM + kbase + c8;
            rb[i][0] = *(const float4*)pB;
            rb[i][1] = *(const float4*)(pB + 4);
        }
    };

    auto store_tile = [&]() {
#pragma unroll
        for (int i = 0; i < 4; ++i) {
            int idx = tid + i * 256;
            int row = idx >> 3;
            int c8  = (idx & 7) << 3;
            ushort8 ta, tb;
#pragma unroll
            for (int j = 0; j < 4; ++j) {
                ta[j]     = f2bf(((const float*)&ra[i][0])[j]);
                ta[j + 4] = f2bf(((const float*)&ra[i][1])[j]);
                tb[j]     = f2bf(((const float*)&rb[i][0])[j]);
                tb[j + 4] = f2bf(((const float*)&rb[i][1])[j]);
            }
            *(ushort8*)&As[row][c8] = ta;
            *(ushort8*)&Bs[row][c8] = tb;
        }
    };

    const int lane = tid & 63;
    const int wid  = tid >> 6;
    const int wr = wid >> 1, wc = wid & 1;
    const int row0 = wr * 64, col0 = wc * 64;
    const int fr = lane & 15;
    const int fg = lane >> 4;

    floatx4 acc[4][4];
#pragma unroll
    for (int m = 0; m < 4; ++m)
#pragma unroll
        for (int n = 0; n < 4; ++n)
            acc[m][n] = (floatx4){0.f, 0.f, 0.f, 0.f};

    load_tile(0);
    for (int kt = 0; kt < FNKT; ++kt) {
        if (kt) __syncthreads();
        store_tile();
        __syncthreads();
        if (kt + 1 < FNKT) load_tile(kt + 1);
#pragma unroll
        for (int kk = 0; kk < 2; ++kk) {
            short8 af[4], bf8[4];
#pragma unroll
            for (int m = 0; m < 4; ++m)
                af[m] = *(const short8*)&As[row0 + m * 16 + fr][kk * 32 + fg * 8];
#pragma unroll
            for (int n = 0; n < 4; ++n)
                bf8[n] = *(const short8*)&Bs[col0 + n * 16 + fr][kk * 32 + fg * 8];
#pragma unroll
            for (int m = 0; m < 4; ++m)
#pragma unroll
                for (int n = 0; n < 4; ++n)
                    acc[m][n] = __builtin_amdgcn_mfma_f32_16x16x32_bf16(
                        af[m], bf8[n], acc[m][n], 0, 0, 0);
        }
    }

#pragma unroll
    for (int n = 0; n < 4; ++n) {
        int col = bcol + col0 + n * 16 + fr;
        if (col >= CLS) continue;
        float bv = bias[col];
#pragma unroll
        for (int m = 0; m < 4; ++m) {
#pragma unroll
            for (int j = 0; j < 4; ++j) {
                int row = brow + row0 + m * 16 + fg * 4 + j;
                float z = acc[m][n][j] + bv;
                out[(size_t)row * CLS + col] = softplus_fast(z) + 1.f;
            }
        }
    }
}

// ---------------- DS combine: one wave per row, shuffle-xor reduce ----------

__global__ __launch_bounds__(256)
void ds_combine(const float* __restrict__ AX, const float* __restrict__ AY,
                float* __restrict__ out)
{
    const int row = blockIdx.x * 4 + (threadIdx.x >> 6);
    const int l = threadIdx.x & 63;
    const float* ax = AX + (size_t)row * CLS;
    const float* ay = AY + (size_t)row * CLS;

    float4 vx[4], vy[4];
    float sx = 0.f, sy = 0.f, sp = 0.f;
#pragma unroll
    for (int c = 0; c < 4; ++c) {
        int idx = l + c * 64;
        if (idx < CLS / 4) {
            vx[c] = *(const float4*)(ax + idx * 4);
            vy[c] = *(const float4*)(ay + idx * 4);
            const float* px = (const float*)&vx[c];
            const float* py = (const float*)&vy[c];
#pragma unroll
            for (int j = 0; j < 4; ++j) {
                sx += px[j]; sy += py[j];
                sp += (px[j] - 1.f) * (py[j] - 1.f);
            }
        }
    }
#pragma unroll
    for (int off = 1; off < 64; off <<= 1) {
        sx += __shfl_xor(sx, off);
        sy += __shfl_xor(sy, off);
        sp += __shfl_xor(sp, off);
    }
    const float S1 = sx, S2 = sy, P = sp;
    const float i1 = 1.f / S1, i2 = 1.f / S2;
    const float u1 = (float)CLS * i1, u2 = (float)CLS * i2;
    const float sb1 = (S1 - (float)CLS) * i1;
    const float sb2 = (S2 - (float)CLS) * i2;
    const float conf = sb1 * sb2 - P * i1 * i2;
    const float denom = 1.f - conf;
    const float idenom = 1.f / denom;
    const float Sa = (float)CLS * denom / (u1 * u2);

#pragma unroll
    for (int c = 0; c < 4; ++c) {
        int idx = l + c * 64;
        if (idx < CLS / 4) {
            float4 vo;
            const float* px = (const float*)&vx[c];
            const float* py = (const float*)&vy[c];
            float* po = (float*)&vo;
#pragma unroll
            for (int j = 0; j < 4; ++j) {
                float b1 = (px[j] - 1.f) * i1;
                float b2 = (py[j] - 1.f) * i2;
                float ba = (b1 * b2 + b1 * u2 + b2 * u1) * idenom;
                po[j] = ba * Sa + 1.f;
            }
            *(float4*)(out + (size_t)row * CLS + idx * 4) = vo;
        }
    }
}

extern "C" void kernel_launch(void* const* d_in, const int* in_sizes, int n_in,
                              void* d_out, int out_size, void* d_ws, size_t ws_size,
                              hipStream_t stream) {
    const float* x  = (const float*)d_in[0];
    const float* y  = (const float*)d_in[1];
    const float* Wx = (const float*)d_in[2];
    const float* bx = (const float*)d_in[3];
    const float* Wy = (const float*)d_in[4];
    const float* by = (const float*)d_in[5];
    float* out = (float*)d_out;
    float* ax = out + (size_t)BATCH_N * CLS;
    float* ay = ax  + (size_t)BATCH_N * CLS;

    const size_t SZ_X = (size_t)BATCH_N * K_DIM;
    const size_t SZ_W = (size_t)NPAD * K_DIM;
    const size_t need = (2 * SZ_X + 2 * SZ_W) * sizeof(ushort); // 75.5 MB

    if (ws_size >= need) {
        ushort* xb  = (ushort*)d_ws;
        ushort* yb  = xb + SZ_X;
        ushort* wxb = yb + SZ_X;
        ushort* wyb = wxb + SZ_W;

        convert_all<<<18432, 256, 0, stream>>>(x, y, Wx, Wy, xb, yb, wxb, wyb);
        gemm8p<<<dim3(NPAD / 256, BATCH_N / 256, 2), 512, 0, stream>>>(
            xb, yb, wxb, wyb, bx, by, ax, ay);
    } else {
        gemm_alpha<<<dim3((CLS + FBN - 1) / FBN, BATCH_N / FBM, 2), 256, 0, stream>>>(
            x, y, Wx, Wy, bx, by, ax, ay);
    }
    ds_combine<<<BATCH_N / 4, 256, 0, stream>>>(ax, ay, out);
}